// Round 2
// baseline (325.565 us; speedup 1.0000x reference)
//
#include <hip/hip_runtime.h>
#include <math.h>

#define NTOK 198
#define CCH  192
#define DIMV 8
#define NB   1024

__device__ __forceinline__ float qgelu(float v) {
    // x * sigmoid(1.702 x)
    return v / (1.0f + __expf(-1.702f * v));
}

// ============ K1: d = qgelu(x @ w_down^T + b_down)  [one 32-token chunk/block] ============
__global__ __launch_bounds__(256) void k1_down(
    const float* __restrict__ x,       // [B,198,192]
    const float* __restrict__ w_down,  // [8,192]
    const float* __restrict__ b_down,  // [8]
    float* __restrict__ d)             // [B,198,8]
{
    const int b   = blockIdx.y;
    const int n0  = blockIdx.x * 32;
    const int ntok = min(32, NTOK - n0);
    const int tid = threadIdx.x;

    __shared__ float s_x[32 * 196];  // stride 196: rows at bank offsets of 4 -> conflict-free b128
    __shared__ float s_w[8 * 196];

    for (int t = tid; t < 8 * 192; t += 256)
        s_w[(t / 192) * 196 + (t % 192)] = w_down[t];

    const float* xb = x + ((size_t)b * NTOK + n0) * CCH;
    const int nf4 = ntok * 48;
    for (int t = tid; t < nf4; t += 256) {
        const int row = t / 48, c4 = t % 48;
        *(float4*)&s_x[row * 196 + c4 * 4] =
            *(const float4*)(xb + (size_t)row * CCH + c4 * 4);
    }
    __syncthreads();

    if (tid < ntok * 8) {
        const int nl = tid >> 3, dim = tid & 7;
        float acc = b_down[dim];
        const float4* xr = (const float4*)&s_x[nl * 196];   // broadcast across 8 dims
        const float4* wr = (const float4*)&s_w[dim * 196];  // 8 rows spread over all 32 banks
        #pragma unroll 12
        for (int c4 = 0; c4 < 48; ++c4) {
            const float4 xv = xr[c4], wv = wr[c4];
            acc += xv.x * wv.x + xv.y * wv.y + xv.z * wv.z + xv.w * wv.w;
        }
        d[((size_t)b * NTOK + n0 + nl) * 8 + dim] = qgelu(acc);  // coalesced
    }
}

// ============ K2: conv3x3 + qgelu + up-proj  [4 tokens/block] ============
__global__ __launch_bounds__(192) void k2_conv_up(
    const float* __restrict__ d,       // [B,198,8]
    const float* __restrict__ conv_w,  // [8,8,3,3]
    const float* __restrict__ conv_b,  // [8]
    const float* __restrict__ w_up,    // [192,8]
    const float* __restrict__ b_up,    // [192]
    float* __restrict__ out)           // [B,198,192]
{
    const int b   = blockIdx.y;
    const int n0  = blockIdx.x * 4;
    const int tid = threadIdx.x;

    __shared__ float s_d2[4][8];

    if (tid < 32) {
        const int tl = tid >> 3, o = tid & 7;
        const int n = n0 + tl;
        if (n < NTOK) {
            if (n == 1) {
                s_d2[tl][o] = 0.0f;  // dist token zeroed; qgelu(0)=0
            } else {
                float acc = conv_b[o];
                const float* db = d + (size_t)b * NTOK * 8;
                if (n == 0) {  // cls: only center tap
                    const float4 lo = *(const float4*)(db);
                    const float4 hi = *(const float4*)(db + 4);
                    const float* cw = conv_w + o * 72;  // [i][k], k=4
                    acc += lo.x * cw[0*9+4] + lo.y * cw[1*9+4] + lo.z * cw[2*9+4] + lo.w * cw[3*9+4]
                         + hi.x * cw[4*9+4] + hi.y * cw[5*9+4] + hi.z * cw[6*9+4] + hi.w * cw[7*9+4];
                } else {
                    const int pos = n - 2, h = pos / 14, w = pos % 14;
                    const float* cw = conv_w + o * 72;
                    #pragma unroll
                    for (int dh = -1; dh <= 1; ++dh) {
                        const int hh = h + dh;
                        if (hh < 0 || hh > 13) continue;
                        #pragma unroll
                        for (int dw = -1; dw <= 1; ++dw) {
                            const int ww = w + dw;
                            if (ww < 0 || ww > 13) continue;
                            const int tok = 2 + hh * 14 + ww;
                            const int k   = (dh + 1) * 3 + (dw + 1);
                            const float4 lo = *(const float4*)(db + tok * 8);
                            const float4 hi = *(const float4*)(db + tok * 8 + 4);
                            acc += lo.x * cw[0*9+k] + lo.y * cw[1*9+k] + lo.z * cw[2*9+k] + lo.w * cw[3*9+k]
                                 + hi.x * cw[4*9+k] + hi.y * cw[5*9+k] + hi.z * cw[6*9+k] + hi.w * cw[7*9+k];
                        }
                    }
                }
                s_d2[tl][o] = qgelu(acc);
            }
        }
    }
    __syncthreads();

    const int tl = tid / 48, c4 = tid % 48;
    const int n = n0 + tl;
    if (n < NTOK) {
        float w_r[4][8];
        #pragma unroll
        for (int cc = 0; cc < 4; ++cc) {
            const float4 wa = *(const float4*)(w_up + (c4 * 4 + cc) * 8);
            const float4 wb = *(const float4*)(w_up + (c4 * 4 + cc) * 8 + 4);
            w_r[cc][0] = wa.x; w_r[cc][1] = wa.y; w_r[cc][2] = wa.z; w_r[cc][3] = wa.w;
            w_r[cc][4] = wb.x; w_r[cc][5] = wb.y; w_r[cc][6] = wb.z; w_r[cc][7] = wb.w;
        }
        const float4 bu = *(const float4*)(b_up + c4 * 4);
        const float4 da = *(const float4*)&s_d2[tl][0];
        const float4 dv = *(const float4*)&s_d2[tl][4];
        float accs[4] = {bu.x, bu.y, bu.z, bu.w};
        #pragma unroll
        for (int cc = 0; cc < 4; ++cc) {
            accs[cc] += da.x * w_r[cc][0] + da.y * w_r[cc][1]
                      + da.z * w_r[cc][2] + da.w * w_r[cc][3]
                      + dv.x * w_r[cc][4] + dv.y * w_r[cc][5]
                      + dv.z * w_r[cc][6] + dv.w * w_r[cc][7];
        }
        *(float4*)(out + ((size_t)b * NTOK + n) * CCH + c4 * 4) =
            make_float4(accs[0], accs[1], accs[2], accs[3]);
    }
}

// ============ Fallback: previous fused single-kernel (used only if ws too small) ============
__global__ __launch_bounds__(256) void convpass_fused(
    const float* __restrict__ x, const float* __restrict__ w_down,
    const float* __restrict__ b_down, const float* __restrict__ conv_w,
    const float* __restrict__ conv_b, const float* __restrict__ w_up,
    const float* __restrict__ b_up, float* __restrict__ out)
{
    const int b   = blockIdx.x;
    const int tid = threadIdx.x;
    __shared__ float s_x[32 * 196];
    __shared__ float s_wdn[8 * 196];
    __shared__ float s_d[NTOK * 9];
    float* s_d2 = s_x;
    float* s_cw = s_x + NTOK * 8;

    for (int t = tid; t < 8 * 192; t += 256)
        s_wdn[(t / 192) * 196 + (t % 192)] = w_down[t];

    const float* xb = x + (size_t)b * NTOK * CCH;
    for (int ch = 0; ch < 7; ++ch) {
        const int n0 = ch * 32;
        const int ntok = min(32, NTOK - n0);
        __syncthreads();
        const int nf4 = ntok * 48;
        for (int t = tid; t < nf4; t += 256) {
            int row = t / 48, c4 = t % 48;
            *(float4*)(&s_x[row * 196 + c4 * 4]) =
                *(const float4*)(xb + (size_t)(n0 + row) * CCH + c4 * 4);
        }
        __syncthreads();
        if (tid < ntok * 8) {
            const int nl = tid >> 3, dim = tid & 7;
            float acc = b_down[dim];
            const float4* xr = (const float4*)(&s_x[nl * 196]);
            const float4* wr = (const float4*)(&s_wdn[dim * 196]);
            #pragma unroll 8
            for (int c4 = 0; c4 < 48; ++c4) {
                float4 xv = xr[c4], wv = wr[c4];
                acc += xv.x * wv.x + xv.y * wv.y + xv.z * wv.z + xv.w * wv.w;
            }
            s_d[(n0 + nl) * 9 + dim] = qgelu(acc);
        }
    }
    __syncthreads();
    for (int t = tid; t < 576; t += 256) s_cw[t] = conv_w[t];
    __syncthreads();
    for (int j = tid; j < 1584; j += 256) {
        if (j < 1568) {
            const int pos = j >> 3, o = j & 7;
            const int h = pos / 14, w = pos % 14;
            float acc = conv_b[o];
            for (int dh = -1; dh <= 1; ++dh) {
                const int hh = h + dh;
                if (hh < 0 || hh > 13) continue;
                for (int dw = -1; dw <= 1; ++dw) {
                    const int ww = w + dw;
                    if (ww < 0 || ww > 13) continue;
                    const int tok = 2 + hh * 14 + ww;
                    const int k = (dh + 1) * 3 + (dw + 1);
                    for (int i = 0; i < 8; ++i)
                        acc += s_d[tok * 9 + i] * s_cw[(o * 8 + i) * 9 + k];
                }
            }
            s_d2[(2 + pos) * 8 + o] = qgelu(acc);
        } else if (j < 1576) {
            const int o = j - 1568;
            float acc = conv_b[o];
            for (int i = 0; i < 8; ++i)
                acc += s_d[0 * 9 + i] * s_cw[(o * 8 + i) * 9 + 4];
            s_d2[0 * 8 + o] = qgelu(acc);
        } else {
            s_d2[1 * 8 + (j - 1576)] = 0.0f;
        }
    }
    __syncthreads();
    if (tid < 240) {
        const int c4 = tid % 48;
        const int n_off = tid / 48;
        float w_r[4][8];
        for (int cc = 0; cc < 4; ++cc) {
            float4 wa = *(const float4*)(w_up + (c4 * 4 + cc) * 8);
            float4 wb = *(const float4*)(w_up + (c4 * 4 + cc) * 8 + 4);
            w_r[cc][0] = wa.x; w_r[cc][1] = wa.y; w_r[cc][2] = wa.z; w_r[cc][3] = wa.w;
            w_r[cc][4] = wb.x; w_r[cc][5] = wb.y; w_r[cc][6] = wb.z; w_r[cc][7] = wb.w;
        }
        const float4 bu = *(const float4*)(b_up + c4 * 4);
        float* outb = out + (size_t)b * NTOK * CCH;
        for (int n = n_off; n < NTOK; n += 5) {
            const float4 da = *(const float4*)(&s_d2[n * 8]);
            const float4 db = *(const float4*)(&s_d2[n * 8 + 4]);
            float accs[4] = {bu.x, bu.y, bu.z, bu.w};
            for (int cc = 0; cc < 4; ++cc) {
                accs[cc] += da.x * w_r[cc][0] + da.y * w_r[cc][1]
                          + da.z * w_r[cc][2] + da.w * w_r[cc][3]
                          + db.x * w_r[cc][4] + db.y * w_r[cc][5]
                          + db.z * w_r[cc][6] + db.w * w_r[cc][7];
            }
            *(float4*)(outb + (size_t)n * CCH + c4 * 4) =
                make_float4(accs[0], accs[1], accs[2], accs[3]);
        }
    }
}

extern "C" void kernel_launch(void* const* d_in, const int* in_sizes, int n_in,
                              void* d_out, int out_size, void* d_ws, size_t ws_size,
                              hipStream_t stream) {
    const float* x      = (const float*)d_in[0];
    const float* w_down = (const float*)d_in[1];
    const float* b_down = (const float*)d_in[2];
    const float* conv_w = (const float*)d_in[3];
    const float* conv_b = (const float*)d_in[4];
    const float* w_up   = (const float*)d_in[5];
    const float* b_up   = (const float*)d_in[6];
    float* out = (float*)d_out;

    const size_t d_bytes = (size_t)NB * NTOK * DIMV * sizeof(float);
    if (ws_size >= d_bytes) {
        float* d = (float*)d_ws;
        k1_down<<<dim3(7, NB), dim3(256), 0, stream>>>(x, w_down, b_down, d);
        k2_conv_up<<<dim3(50, NB), dim3(192), 0, stream>>>(d, conv_w, conv_b, w_up, b_up, out);
    } else {
        convpass_fused<<<dim3(NB), dim3(256), 0, stream>>>(
            x, w_down, b_down, conv_w, conv_b, w_up, b_up, out);
    }
}

// Round 3
// 130.551 us; speedup vs baseline: 2.4938x; 2.4938x over previous
//
#include <hip/hip_runtime.h>
#include <math.h>

#define NTOK 198
#define CCH  192
#define DIMV 8

__device__ __forceinline__ float qgelu(float v) {
    return v / (1.0f + __expf(-1.702f * v));  // x * sigmoid(1.702 x)
}

// ============ K1: d = qgelu(x @ w_down^T + b_down) ============
// wave = 8 flat token-rows x 8 c-chunk lanes; no x staging, one barrier total.
__global__ __launch_bounds__(256) void k1_down(
    const float* __restrict__ x,       // [B*198, 192] flat rows
    const float* __restrict__ w_down,  // [8,192]
    const float* __restrict__ b_down,  // [8]
    float* __restrict__ d,             // [B*198, 8]
    int n_groups)                      // total 8-row groups
{
    __shared__ float s_w[8 * 192];
    __shared__ float s_b[8];
    const int tid = threadIdx.x;
    for (int t = tid; t < 8 * 192; t += 256) s_w[t] = w_down[t];
    if (tid < 8) s_b[tid] = b_down[tid];
    __syncthreads();

    const int lane  = tid & 63;
    const int t_sub = lane >> 3;  // token within group (0..7)
    const int k     = lane & 7;   // c-chunk (24 floats each)
    const int gwave = blockIdx.x * 4 + (tid >> 6);

    #pragma unroll 1
    for (int i = 0; i < 6; ++i) {
        const int g = gwave * 6 + i;
        if (g >= n_groups) break;
        const size_t row = (size_t)g * 8 + t_sub;
        const float* xr = x + row * CCH + k * 24;

        float acc[8] = {0.f, 0.f, 0.f, 0.f, 0.f, 0.f, 0.f, 0.f};
        #pragma unroll
        for (int j = 0; j < 6; ++j) {
            const float4 xv = *(const float4*)(xr + j * 4);
            const int c = k * 24 + j * 4;
            #pragma unroll
            for (int dm = 0; dm < 8; ++dm) {
                // lanes differ in k: stride-96B -> 4 bank-groups x 2-way: conflict-free
                const float4 wv = *(const float4*)&s_w[dm * CCH + c];
                acc[dm] += xv.x * wv.x + xv.y * wv.y + xv.z * wv.z + xv.w * wv.w;
            }
        }
        // reduce the 8 c-chunk lanes (xor within 8-lane group)
        #pragma unroll
        for (int dm = 0; dm < 8; ++dm) {
            float v = acc[dm];
            v += __shfl_xor(v, 1);
            v += __shfl_xor(v, 2);
            v += __shfl_xor(v, 4);
            acc[dm] = v;
        }
        // lane writes dim=k of token t_sub: d[row*8+k] = g*64+lane -> fully coalesced
        d[row * 8 + k] = qgelu(acc[k] + s_b[k]);
    }
}

// ============ K2: conv3x3 + qgelu + up-proj, one block per batch element ============
__global__ __launch_bounds__(256) void k2_conv_up(
    const float* __restrict__ d,       // [B,198,8]
    const float* __restrict__ conv_w,  // [8,8,3,3]
    const float* __restrict__ conv_b,  // [8]
    const float* __restrict__ w_up,    // [192,8]
    const float* __restrict__ b_up,    // [192]
    float* __restrict__ out)           // [B,198,192]
{
    const int b   = blockIdx.x;
    const int tid = threadIdx.x;

    __shared__ float s_d[NTOK * 9];   // stride 9: conflict-free scalar conv reads
    __shared__ float s_d2[NTOK * 8];  // stride 8: b128 up-proj reads
    __shared__ float s_cw[576];
    __shared__ float s_cb[8];

    // ---- w_up -> registers (issued early, reused over all 40 stores)
    const int c4 = tid % 48;
    const int tl = tid / 48;  // 0..5 (tl==5 idle in up-proj)
    float w_r[4][8];
    #pragma unroll
    for (int cc = 0; cc < 4; ++cc) {
        const float4 wa = *(const float4*)(w_up + (c4 * 4 + cc) * 8);
        const float4 wb = *(const float4*)(w_up + (c4 * 4 + cc) * 8 + 4);
        w_r[cc][0] = wa.x; w_r[cc][1] = wa.y; w_r[cc][2] = wa.z; w_r[cc][3] = wa.w;
        w_r[cc][4] = wb.x; w_r[cc][5] = wb.y; w_r[cc][6] = wb.z; w_r[cc][7] = wb.w;
    }
    const float4 bu = *(const float4*)(b_up + c4 * 4);

    // ---- stage d[b] into stride-9 LDS (coalesced float4 global reads)
    const float4* db4 = (const float4*)(d + (size_t)b * NTOK * 8);
    for (int t = tid; t < NTOK * 2; t += 256) {
        const float4 v = db4[t];
        const int base = (t >> 1) * 9 + (t & 1) * 4;
        s_d[base + 0] = v.x; s_d[base + 1] = v.y;
        s_d[base + 2] = v.z; s_d[base + 3] = v.w;
    }
    for (int t = tid; t < 576; t += 256) s_cw[t] = conv_w[t];
    if (tid < 8) s_cb[tid] = conv_b[tid];
    __syncthreads();

    // ---- conv 3x3 + qgelu -> s_d2 (all 256 threads)
    for (int j = tid; j < NTOK * 8; j += 256) {
        const int n = j >> 3, o = j & 7;
        if (n == 1) {             // dist token zeroed; qgelu(0)=0
            s_d2[j] = 0.0f;
        } else if (n == 0) {      // cls: center tap only
            float acc = s_cb[o];
            #pragma unroll
            for (int i = 0; i < 8; ++i)
                acc += s_d[i] * s_cw[(o * 8 + i) * 9 + 4];
            s_d2[j] = qgelu(acc);
        } else {
            const int pos = n - 2, h = pos / 14, w = pos % 14;
            float acc = s_cb[o];
            #pragma unroll
            for (int dh = -1; dh <= 1; ++dh) {
                const int hh = h + dh;
                if (hh < 0 || hh > 13) continue;
                #pragma unroll
                for (int dw = -1; dw <= 1; ++dw) {
                    const int ww = w + dw;
                    if (ww < 0 || ww > 13) continue;
                    const int tok = 2 + hh * 14 + ww;
                    const int kk  = (dh + 1) * 3 + (dw + 1);
                    #pragma unroll
                    for (int i = 0; i < 8; ++i)
                        acc += s_d[tok * 9 + i] * s_cw[(o * 8 + i) * 9 + kk];
                }
            }
            s_d2[j] = qgelu(acc);
        }
    }
    __syncthreads();

    // ---- up-proj: out[n][c4*4..+3] for n = tl, tl+5, ...
    if (tl < 5) {
        float* outb = out + (size_t)b * NTOK * CCH;
        for (int n = tl; n < NTOK; n += 5) {
            const float4 da = *(const float4*)&s_d2[n * 8];
            const float4 dv = *(const float4*)&s_d2[n * 8 + 4];
            float accs[4] = {bu.x, bu.y, bu.z, bu.w};
            #pragma unroll
            for (int cc = 0; cc < 4; ++cc) {
                accs[cc] += da.x * w_r[cc][0] + da.y * w_r[cc][1]
                          + da.z * w_r[cc][2] + da.w * w_r[cc][3]
                          + dv.x * w_r[cc][4] + dv.y * w_r[cc][5]
                          + dv.z * w_r[cc][6] + dv.w * w_r[cc][7];
            }
            *(float4*)(outb + (size_t)n * CCH + c4 * 4) =
                make_float4(accs[0], accs[1], accs[2], accs[3]);
        }
    }
}

extern "C" void kernel_launch(void* const* d_in, const int* in_sizes, int n_in,
                              void* d_out, int out_size, void* d_ws, size_t ws_size,
                              hipStream_t stream) {
    const float* x      = (const float*)d_in[0];
    const float* w_down = (const float*)d_in[1];
    const float* b_down = (const float*)d_in[2];
    const float* conv_w = (const float*)d_in[3];
    const float* conv_b = (const float*)d_in[4];
    const float* w_up   = (const float*)d_in[5];
    const float* b_up   = (const float*)d_in[6];
    float* out = (float*)d_out;

    const int B = in_sizes[0] / (NTOK * CCH);  // 1024
    const int rows = B * NTOK;
    const int n_groups = (rows + 7) / 8;              // 8-row groups
    const int n_waves  = (n_groups + 5) / 6;          // 6 groups per wave
    const int k1_blocks = (n_waves + 3) / 4;          // 4 waves per block

    float* dbuf = (float*)d_ws;  // B*198*8 floats = 6.5 MB (ws is large enough; R2 verified)
    k1_down<<<dim3(k1_blocks), dim3(256), 0, stream>>>(x, w_down, b_down, dbuf, n_groups);
    k2_conv_up<<<dim3(B), dim3(256), 0, stream>>>(dbuf, conv_w, conv_b, w_up, b_up, out);
}

// Round 6
// 106.016 us; speedup vs baseline: 3.0709x; 1.2314x over previous
//
#include <hip/hip_runtime.h>
#include <math.h>

#define NTOK 198
#define CCH  192
#define DIMV 8
#define K1_NG 3   // 16-row groups per wave

typedef float vf4 __attribute__((ext_vector_type(4)));  // clang-native for nontemporal

__device__ __forceinline__ float qgelu(float v) {
    return v / (1.0f + __expf(-1.702f * v));  // x * sigmoid(1.702 x)
}

// ============ K1: d = qgelu(x @ w_down^T + b_down) ============
// wave = 8 tokens x 8 c-chunk lanes, TWO rows per lane per group (w reuse).
__global__ __launch_bounds__(256, 4) void k1_down(
    const float* __restrict__ x,       // [B*198, 192] flat rows
    const float* __restrict__ w_down,  // [8,192]
    const float* __restrict__ b_down,  // [8]
    float* __restrict__ d,             // [B*198, 8]
    int n_groups, int n_rows)
{
    __shared__ float s_w[8 * CCH];
    const int tid = threadIdx.x;
    for (int t = tid; t < 8 * CCH; t += 256) s_w[t] = w_down[t];
    __syncthreads();

    const int lane  = tid & 63;
    const int t_sub = lane >> 3;      // token-slot 0..7
    const int k     = lane & 7;       // c-chunk (24 floats)
    const int gwave = blockIdx.x * 4 + (tid >> 6);
    const float bd  = b_down[k];

    #pragma unroll 1
    for (int i = 0; i < K1_NG; ++i) {
        const int g = gwave * K1_NG + i;
        if (g >= n_groups) break;
        const size_t rA = (size_t)g * 16 + t_sub;
        const size_t rB = rA + 8;
        if ((int)rB >= n_rows) break;  // (exact for B=1024: 202752 % 16 == 0)

        const float* pA = x + rA * CCH + k * 24;
        const float* pB = x + rB * CCH + k * 24;
        float4 xa[6], xb[6];
        #pragma unroll
        for (int j = 0; j < 6; ++j) {
            xa[j] = *(const float4*)(pA + 4 * j);
            xb[j] = *(const float4*)(pB + 4 * j);
        }

        float accA[8] = {0,0,0,0,0,0,0,0};
        float accB[8] = {0,0,0,0,0,0,0,0};
        #pragma unroll
        for (int j = 0; j < 6; ++j) {
            #pragma unroll
            for (int dm = 0; dm < 8; ++dm) {
                // per instr: 8 distinct addrs (k), 96B stride -> 4 bank-quads x 2-way: ~free
                const float4 wv = *(const float4*)&s_w[dm * CCH + k * 24 + j * 4];
                accA[dm] += xa[j].x * wv.x + xa[j].y * wv.y + xa[j].z * wv.z + xa[j].w * wv.w;
                accB[dm] += xb[j].x * wv.x + xb[j].y * wv.y + xb[j].z * wv.z + xb[j].w * wv.w;
            }
        }

        float outA = 0.f, outB = 0.f;
        #pragma unroll
        for (int dm = 0; dm < 8; ++dm) {
            float vA = accA[dm];
            vA += __shfl_xor(vA, 1); vA += __shfl_xor(vA, 2); vA += __shfl_xor(vA, 4);
            float vB = accB[dm];
            vB += __shfl_xor(vB, 1); vB += __shfl_xor(vB, 2); vB += __shfl_xor(vB, 4);
            outA = (dm == k) ? vA : outA;
            outB = (dm == k) ? vB : outB;
        }
        // store: addr = g*128 + lane (A), +64 (B) -> fully coalesced 256B/wave
        d[rA * 8 + k] = qgelu(outA + bd);
        d[rB * 8 + k] = qgelu(outB + bd);
    }
}

// ============ K2: conv3x3 + qgelu + up-proj  [40-token chunk per block] ============
__global__ __launch_bounds__(256) void k2_conv_up(
    const float* __restrict__ d,       // [B,198,8]
    const float* __restrict__ conv_w,  // [8,8,3,3]
    const float* __restrict__ conv_b,  // [8]
    const float* __restrict__ w_up,    // [192,8]
    const float* __restrict__ b_up,    // [192]
    float* __restrict__ out)           // [B,198,192]
{
    const int b     = blockIdx.y;
    const int chunk = blockIdx.x;
    const int n0    = chunk * 40;
    const int nt    = min(40, NTOK - n0);
    const int tid   = threadIdx.x;

    __shared__ float s_d[NTOK * 9];   // stride 9 -> conflict-free conv reads
    __shared__ float s_cw[576];       // transposed: [kk][i][o]
    __shared__ float s_cb[8];
    __shared__ float s_d2[40 * 8];

    // w_up -> registers (reused over 8 stores)
    const int c4 = tid % 48;
    const int tl = tid / 48;  // 0..5 (tl==5 idle in up-proj)
    float w_r[4][8];
    #pragma unroll
    for (int cc = 0; cc < 4; ++cc) {
        const float4 wa = *(const float4*)(w_up + (c4 * 4 + cc) * 8);
        const float4 wb = *(const float4*)(w_up + (c4 * 4 + cc) * 8 + 4);
        w_r[cc][0] = wa.x; w_r[cc][1] = wa.y; w_r[cc][2] = wa.z; w_r[cc][3] = wa.w;
        w_r[cc][4] = wb.x; w_r[cc][5] = wb.y; w_r[cc][6] = wb.z; w_r[cc][7] = wb.w;
    }
    const float4 bu = *(const float4*)(b_up + c4 * 4);

    // stage d[b] (full row incl. halo) into stride-9 LDS
    const float4* db4 = (const float4*)(d + (size_t)b * NTOK * 8);
    for (int t = tid; t < NTOK * 2; t += 256) {
        const float4 v = db4[t];
        const int base = (t >> 1) * 9 + (t & 1) * 4;
        s_d[base + 0] = v.x; s_d[base + 1] = v.y;
        s_d[base + 2] = v.z; s_d[base + 3] = v.w;
    }
    // conv weights transposed: s_cw[kk*64 + i*8 + o] = conv_w[o][i][kk]
    // (strided loop: 576 > blockDim, must iterate!)
    for (int t = tid; t < 576; t += 256) {
        const int kk = t >> 6, rem = t & 63, i = rem >> 3, o = rem & 7;
        s_cw[t] = conv_w[(o * 8 + i) * 9 + kk];
    }
    if (tid < 8) s_cb[tid] = conv_b[tid];
    __syncthreads();

    // conv 3x3 + qgelu -> s_d2 (reads broadcast/conflict-free)
    for (int j = tid; j < nt * 8; j += 256) {
        const int nr = j >> 3, o = j & 7;
        const int n = n0 + nr;
        if (n == 1) {
            s_d2[j] = 0.0f;            // dist token zeroed; qgelu(0)=0
        } else if (n == 0) {           // cls: center tap only
            float acc = s_cb[o];
            #pragma unroll
            for (int i = 0; i < 8; ++i)
                acc += s_d[i] * s_cw[4 * 64 + i * 8 + o];
            s_d2[j] = qgelu(acc);
        } else {
            const int pos = n - 2, h = pos / 14, w = pos % 14;
            float acc = s_cb[o];
            #pragma unroll
            for (int dh = -1; dh <= 1; ++dh) {
                const int hh = h + dh;
                if (hh < 0 || hh > 13) continue;
                #pragma unroll
                for (int dw = -1; dw <= 1; ++dw) {
                    const int ww = w + dw;
                    if (ww < 0 || ww > 13) continue;
                    const int tok = 2 + hh * 14 + ww;
                    const int kk  = (dh + 1) * 3 + (dw + 1);
                    #pragma unroll
                    for (int i = 0; i < 8; ++i)
                        acc += s_d[tok * 9 + i] * s_cw[kk * 64 + i * 8 + o];
                }
            }
            s_d2[j] = qgelu(acc);
        }
    }
    __syncthreads();

    // up-proj: thread (c4, tl) does tokens nr = tl, tl+5, ...
    if (tl < 5) {
        float* outb = out + ((size_t)b * NTOK + n0) * CCH;
        for (int nr = tl; nr < nt; nr += 5) {
            const float4 da = *(const float4*)&s_d2[nr * 8];
            const float4 dv = *(const float4*)&s_d2[nr * 8 + 4];
            float accs[4] = {bu.x, bu.y, bu.z, bu.w};
            #pragma unroll
            for (int cc = 0; cc < 4; ++cc) {
                accs[cc] += da.x * w_r[cc][0] + da.y * w_r[cc][1]
                          + da.z * w_r[cc][2] + da.w * w_r[cc][3]
                          + dv.x * w_r[cc][4] + dv.y * w_r[cc][5]
                          + dv.z * w_r[cc][6] + dv.w * w_r[cc][7];
            }
            const vf4 r = {accs[0], accs[1], accs[2], accs[3]};
            __builtin_nontemporal_store(r, (vf4*)(outb + (size_t)nr * CCH + c4 * 4));
        }
    }
}

extern "C" void kernel_launch(void* const* d_in, const int* in_sizes, int n_in,
                              void* d_out, int out_size, void* d_ws, size_t ws_size,
                              hipStream_t stream) {
    const float* x      = (const float*)d_in[0];
    const float* w_down = (const float*)d_in[1];
    const float* b_down = (const float*)d_in[2];
    const float* conv_w = (const float*)d_in[3];
    const float* conv_b = (const float*)d_in[4];
    const float* w_up   = (const float*)d_in[5];
    const float* b_up   = (const float*)d_in[6];
    float* out = (float*)d_out;

    const int B = in_sizes[0] / (NTOK * CCH);   // 1024
    const int n_rows   = B * NTOK;              // 202752
    const int n_groups = n_rows / 16;           // 12672 (exact)
    const int n_waves  = (n_groups + K1_NG - 1) / K1_NG;
    const int k1_blocks = (n_waves + 3) / 4;    // 1056

    float* dbuf = (float*)d_ws;  // B*198*8 floats = 6.5 MB
    k1_down<<<dim3(k1_blocks), dim3(256), 0, stream>>>(x, w_down, b_down, dbuf,
                                                       n_groups, n_rows);
    k2_conv_up<<<dim3(5, B), dim3(256), 0, stream>>>(dbuf, conv_w, conv_b, w_up, b_up, out);
}